// Round 12
// baseline (32.923 us; speedup 1.0000x reference)
//
#include <hip/hip_runtime.h>
#include <math.h>

#define B_SZ 4
#define C_IN 64
#define HW_ 576
#define PPLANE 728                    // 26*28 padded plane of h2 (channel pair)
#define XH_N   (B_SZ * 32 * PPLANE)   // 93184
#define WQH_N  (192 * 32 * 9)         // 55296: ((g*32+icp)*3+o)*9+t, oc=g+64*o
#define WOH_N  (64 * 32 * 9)          // 18432: (oc*32+icp)*9+t
#define SLAB16 5824                   // 32*PPLANE h2 = 93184 B = 5824 uint4

typedef _Float16 h2 __attribute__((ext_vector_type(2)));
typedef _Float16 h4 __attribute__((ext_vector_type(4)));
typedef _Float16 h8 __attribute__((ext_vector_type(8)));

static __device__ __forceinline__ h2 lo2(h4 v) { return __builtin_shufflevector(v, v, 0, 1); }
static __device__ __forceinline__ h2 hi2(h4 v) { return __builtin_shufflevector(v, v, 2, 3); }

static __device__ __forceinline__ float dot2(h2 a, h2 b, float c) {
#if __has_builtin(__builtin_amdgcn_fdot2)
  return __builtin_amdgcn_fdot2(a, b, c, false);
#else
  return c + (float)a.x * (float)b.x + (float)a.y * (float)b.y;
#endif
}

static __device__ __forceinline__ float frcp(float d) {
#if __has_builtin(__builtin_amdgcn_rcpf)
  return __builtin_amdgcn_rcpf(d);
#else
  return 1.0f / d;
#endif
}

// ---------------- K1: BN stats (redundant per block) + pack x & weights ----
__global__ __launch_bounds__(256)
void stats_pack_kernel(const float* __restrict__ x, const float* __restrict__ gamma,
                       const float* __restrict__ beta, const float* __restrict__ wq,
                       const float* __restrict__ wo, h2* __restrict__ xh,
                       h2* __restrict__ wqh, h2* __restrict__ woh) {
  const int bid = blockIdx.x, tid = threadIdx.x;
  if (bid < 128) {
    const int icp = bid & 31, b = bid >> 5;
    __shared__ float rs[4], rss[4], ab[4];
    const int c = icp * 2 + (tid >> 7);
    float s = 0.f, ss = 0.f;
    for (int i = (tid & 127); i < B_SZ * HW_; i += 128) {
      int b2 = i / HW_, px = i - b2 * HW_;
      float v = x[(b2 * C_IN + c) * HW_ + px];
      s += v; ss = fmaf(v, v, ss);
    }
#pragma unroll
    for (int off = 32; off > 0; off >>= 1) {
      s += __shfl_down(s, off); ss += __shfl_down(ss, off);
    }
    if ((tid & 63) == 0) { rs[tid >> 6] = s; rss[tid >> 6] = ss; }
    __syncthreads();
    if (tid < 2) {
      float S = rs[tid * 2] + rs[tid * 2 + 1], SS = rss[tid * 2] + rss[tid * 2 + 1];
      const float inv_n = 1.f / (B_SZ * HW_);
      float mean = S * inv_n;
      float var  = SS * inv_n - mean * mean;
      float a = rsqrtf(var + 1e-5f) * gamma[icp * 2 + tid];
      ab[tid * 2] = a;
      ab[tid * 2 + 1] = fmaf(-mean, a, beta[icp * 2 + tid]);
    }
    __syncthreads();
    const float a0 = ab[0], b0 = ab[1], a1 = ab[2], b1 = ab[3];
    h2* plane = xh + (size_t)(b * 32 + icp) * PPLANE;
    const float* src0 = x + (size_t)(b * C_IN + icp * 2) * HW_;
    for (int e = tid; e < PPLANE; e += 256) {
      int rrow = e / 28, ecol = e - rrow * 28;
      int yy = rrow - 1, xx = ecol - 1;
      float f0 = 0.f, f1 = 0.f;
      if ((unsigned)yy < 24u && (unsigned)xx < 24u) {
        f0 = fmaf(src0[yy * 24 + xx],       a0, b0);
        f1 = fmaf(src0[HW_ + yy * 24 + xx], a1, b1);
      }
      h2 v; v.x = (_Float16)f0; v.y = (_Float16)f1;
      plane[e] = v;
    }
  } else {
    const int base = (bid - 128) * 576;
    for (int t = base + tid; t < base + 576; t += 256) {
      if (t < WQH_N) {
        int tt = t % 9; int r = t / 9;
        int o = r % 3; r /= 3;
        int icp = r % 32; int g = r / 32;
        int oc = g + 64 * o, ic = icp * 2;   // q/k/v of channel g in one block
        h2 v;
        v.x = (_Float16)wq[(oc * C_IN + ic) * 9 + tt];
        v.y = (_Float16)wq[(oc * C_IN + ic + 1) * 9 + tt];
        wqh[t] = v;
      } else {
        int t0 = t - WQH_N;
        int tt = t0 % 9; int r = t0 / 9;
        int icp = r % 32; int oc = r / 32;
        int ic = icp * 2;
        h2 v;  // scale 4096: dodge f16 subnormals (w_out ~ 7e-5)
        v.x = (_Float16)(wo[(oc * C_IN + ic) * 9 + tt] * 4096.f);
        v.y = (_Float16)(wo[(oc * C_IN + ic + 1) * 9 + tt] * 4096.f);
        woh[t0] = v;
      }
    }
  }
}

// ---------------- K2: fused qkv conv + barycentric rank-1 attention --------
// Planes staged to LDS (93KB slab copy) -> conv data from LDS, weights
// broadcast from LDS. Attention buffers overlay the (dead) plane region.
__global__ __launch_bounds__(576)
void qkv_attn_kernel(const h2* __restrict__ xh, const h2* __restrict__ wqh,
                     h2* __restrict__ outv) {
  const int bid = blockIdx.x, tid = threadIdx.x;
  const int b = bid >> 6, c = bid & 63;
  const int sub = tid / 288;
  const int r = tid - sub * 288;
  const int y = r / 12, x0 = (r % 12) * 2;

  __shared__ __align__(16) char smem[97280];
  // [0, 93184): input planes (conv phase) -> overlaid after conv by:
  //   cb [0,6912) | kvs [6912,11520) | qs [11520,13824) | red [13824,14472)
  //   FGf [14472,14544) | red2 [14560,26080)
  // [93184, 97280): Wl weights [32 rows][32 h2]
  h2*    Wl  = (h2*)(smem + 93184);
  float* cb  = (float*)smem;
  float2* kvs = (float2*)(smem + 6912);
  float* qs  = (float*)(smem + 11520);
  float* red = (float*)(smem + 13824);
  float* FGf = (float*)(smem + 14472);
  float* red2 = (float*)(smem + 14560);

  // stage the block's 32 input planes (93KB) into LDS
  {
    const uint4* src = (const uint4*)(xh + (size_t)b * 32 * PPLANE);
    uint4* dst = (uint4*)smem;
    for (int j = tid; j < SLAB16; j += 576) dst[j] = src[j];
  }
  // stage weights: 27 used h2 per icp row, rows padded to 32 h2 (128B)
  for (int j = tid; j < 864; j += 576) {
    int icp = j / 27, rem = j - icp * 27;
    Wl[icp * 32 + rem] = wqh[c * 864 + j];
  }
  __syncthreads();

  float acc[3][2] = {{0.f, 0.f}, {0.f, 0.f}, {0.f, 0.f}};
  const int icp0 = sub * 16;
  const int yo = y * 28 + x0;
  const h2* dbase = (const h2*)smem + icp0 * PPLANE + yo;
#pragma unroll
  for (int i = 0; i < 16; ++i) {
    const h2* dp = dbase + i * PPLANE;
    h4 r0a = *(const h4*)(dp);      h4 r0b = *(const h4*)(dp + 2);
    h4 r1a = *(const h4*)(dp + 28); h4 r1b = *(const h4*)(dp + 30);
    h4 r2a = *(const h4*)(dp + 56); h4 r2b = *(const h4*)(dp + 58);
    const h2* wrow = Wl + (icp0 + i) * 32;
    // size-consistent union: v8[7] = 56 halves == v2[28] = 56 halves.
    union { h8 v8[7]; h2 v2[28]; } W;
#pragma unroll
    for (int j8 = 0; j8 < 7; ++j8) W.v8[j8] = *(const h8*)(wrow + j8 * 4);
#pragma unroll
    for (int o = 0; o < 3; ++o) {
      float a0 = acc[o][0], a1 = acc[o][1];
      a0 = dot2(lo2(r0a), W.v2[o * 9 + 0], a0);  a1 = dot2(hi2(r0a), W.v2[o * 9 + 0], a1);
      a0 = dot2(hi2(r0a), W.v2[o * 9 + 1], a0);  a1 = dot2(lo2(r0b), W.v2[o * 9 + 1], a1);
      a0 = dot2(lo2(r0b), W.v2[o * 9 + 2], a0);  a1 = dot2(hi2(r0b), W.v2[o * 9 + 2], a1);
      a0 = dot2(lo2(r1a), W.v2[o * 9 + 3], a0);  a1 = dot2(hi2(r1a), W.v2[o * 9 + 3], a1);
      a0 = dot2(hi2(r1a), W.v2[o * 9 + 4], a0);  a1 = dot2(lo2(r1b), W.v2[o * 9 + 4], a1);
      a0 = dot2(lo2(r1b), W.v2[o * 9 + 5], a0);  a1 = dot2(hi2(r1b), W.v2[o * 9 + 5], a1);
      a0 = dot2(lo2(r2a), W.v2[o * 9 + 6], a0);  a1 = dot2(hi2(r2a), W.v2[o * 9 + 6], a1);
      a0 = dot2(hi2(r2a), W.v2[o * 9 + 7], a0);  a1 = dot2(lo2(r2b), W.v2[o * 9 + 7], a1);
      a0 = dot2(lo2(r2b), W.v2[o * 9 + 8], a0);  a1 = dot2(hi2(r2b), W.v2[o * 9 + 8], a1);
      acc[o][0] = a0; acc[o][1] = a1;
    }
  }
  __syncthreads();                      // planes dead; cb overlays them
  if (sub == 1) {
#pragma unroll
    for (int o = 0; o < 3; ++o) {
      cb[(o * 288 + r) * 2 + 0] = acc[o][0];
      cb[(o * 288 + r) * 2 + 1] = acc[o][1];
    }
  }
  __syncthreads();
  const float scale_l2e = 0.125f * 1.44269504088896341f;  // 1/sqrt(64)*log2(e)
  if (sub == 0) {
    float q0 = acc[0][0] + cb[(0 * 288 + r) * 2 + 0];
    float q1 = acc[0][1] + cb[(0 * 288 + r) * 2 + 1];
    float k0 = acc[1][0] + cb[(1 * 288 + r) * 2 + 0];
    float k1 = acc[1][1] + cb[(1 * 288 + r) * 2 + 1];
    float v0 = acc[2][0] + cb[(2 * 288 + r) * 2 + 0];
    float v1 = acc[2][1] + cb[(2 * 288 + r) * 2 + 1];
    qs[2 * r] = q0 * scale_l2e; qs[2 * r + 1] = q1 * scale_l2e;
    kvs[2 * r] = make_float2(k0, v0);
    kvs[2 * r + 1] = make_float2(k1, v1);
  }
  __syncthreads();

  // ---- barycentric rank-1 attention (thread tid = pixel tid) ----
  const float s = qs[tid];
  float smax = s, smin = s;
#pragma unroll
  for (int off = 32; off > 0; off >>= 1) {
    smax = fmaxf(smax, __shfl_down(smax, off));
    smin = fminf(smin, __shfl_down(smin, off));
  }
  const int wid = tid >> 6;
  if ((tid & 63) == 0) { red[wid] = smax; red[10 + wid] = smin; }
  __syncthreads();
  smax = red[0]; smin = red[10];
#pragma unroll
  for (int w = 1; w < 9; ++w) {
    smax = fmaxf(smax, red[w]); smin = fminf(smin, red[10 + w]);
  }
  const float cc = 0.5f * (smax + smin);
  const float rr = fmaxf(0.5f * (smax - smin), 1e-6f);
  const float COS[9] = { 0.98480775f,  0.86602540f,  0.64278761f,  0.34202014f, 0.f,
                        -0.34202014f, -0.64278761f, -0.86602540f, -0.98480775f };
  const float WJ[9]  = { 0.17364818f, -0.5f,  0.76604444f, -0.93969262f, 1.f,
                        -0.93969262f, 0.76604444f, -0.5f, 0.17364818f };
  float xj[9];
#pragma unroll
  for (int j = 0; j < 9; ++j) xj[j] = fmaf(rr, COS[j], cc);

  const float kk = kvs[tid].x, vv = kvs[tid].y;
  float fj[9], gj[9];
#pragma unroll
  for (int j = 0; j < 9; ++j) {
    float E = __builtin_amdgcn_exp2f(xj[j] * kk);
    gj[j] = E; fj[j] = E * vv;
  }
  // 2-level fold (4-lane groups), LDS transpose, 8-thread column sums.
#pragma unroll
  for (int j = 0; j < 9; ++j) {
    fj[j] += __shfl_xor(fj[j], 1); gj[j] += __shfl_xor(gj[j], 1);
    fj[j] += __shfl_xor(fj[j], 2); gj[j] += __shfl_xor(gj[j], 2);
  }
  if ((tid & 3) == 0) {
    const int row = tid >> 2;       // 0..143
#pragma unroll
    for (int j = 0; j < 9; ++j) {
      red2[row * 20 + j] = fj[j];
      red2[row * 20 + 9 + j] = gj[j];
    }
  }
  __syncthreads();
  if (tid < 144) {
    const int j = tid >> 3, chunk = tid & 7;   // j in 0..17
    float sum = 0.f;
#pragma unroll
    for (int i = 0; i < 18; ++i) sum += red2[(chunk + 8 * i) * 20 + j];
    sum += __shfl_xor(sum, 1);
    sum += __shfl_xor(sum, 2);
    sum += __shfl_xor(sum, 4);
    if (chunk == 0) FGf[j] = sum;
  }
  __syncthreads();

  float num = 0.f, den = 0.f;
#pragma unroll
  for (int j = 0; j < 9; ++j) {
    float d = s - xj[j];
    d = copysignf(fmaxf(fabsf(d), 1e-7f), d);
    float mu = WJ[j] * frcp(d);
    num = fmaf(mu, FGf[j], num);
    den = fmaf(mu, FGf[9 + j], den);
  }
  float outval = num / den;

  const int icp = c >> 1, hc = c & 1;
  _Float16* plane = reinterpret_cast<_Float16*>(outv + ((size_t)(b * 32) + icp) * PPLANE);
  const int yy = tid / 24, xx = tid - yy * 24;
  plane[((yy + 1) * 28 + (xx + 1)) * 2 + hc] = (_Float16)outval;
  if (tid < 100) {  // zero halo (cols 26,27 never read)
    int rrow, e;
    if (tid < 26)      { rrow = 0;            e = tid; }
    else if (tid < 52) { rrow = 25;           e = tid - 26; }
    else if (tid < 76) { rrow = tid - 52 + 1; e = 0; }
    else               { rrow = tid - 76 + 1; e = 25; }
    plane[(rrow * 28 + e) * 2 + hc] = (_Float16)0.f;
  }
}

// ---------------- K3: out conv (OCG=1) + residual + final store ------------
__global__ __launch_bounds__(576)
void conv_out_kernel(const h2* __restrict__ outv, const h2* __restrict__ woh,
                     const float* __restrict__ x, float* __restrict__ out) {
  const int bid = blockIdx.x, tid = threadIdx.x;
  const int b = bid >> 6, oc = bid & 63;
  const int sub = tid / 288;
  const int r = tid - sub * 288;
  const int y = r / 12, x0 = (r % 12) * 2;

  __shared__ __align__(16) char smem[95232];
  // [0, 93184): outv planes (conv) -> cb overlay [0,2304) after conv
  // [93184, 95232): Wl [32 rows][16 h2]
  h2* Wl = (h2*)(smem + 93184);

  {
    const uint4* src = (const uint4*)(outv + (size_t)b * 32 * PPLANE);
    uint4* dst = (uint4*)smem;
    for (int j = tid; j < SLAB16; j += 576) dst[j] = src[j];
  }
  for (int j = tid; j < 288; j += 576) {
    int icp = j / 9, rem = j - icp * 9;
    Wl[icp * 16 + rem] = woh[oc * 288 + j];
  }
  __syncthreads();

  float a0 = 0.f, a1 = 0.f;
  const int icp0 = sub * 16;
  const int yo = y * 28 + x0;
  const h2* dbase = (const h2*)smem + icp0 * PPLANE + yo;
#pragma unroll
  for (int i = 0; i < 16; ++i) {
    const h2* dp = dbase + i * PPLANE;
    h4 r0a = *(const h4*)(dp);      h4 r0b = *(const h4*)(dp + 2);
    h4 r1a = *(const h4*)(dp + 28); h4 r1b = *(const h4*)(dp + 30);
    h4 r2a = *(const h4*)(dp + 56); h4 r2b = *(const h4*)(dp + 58);
    const h2* wrow = Wl + (icp0 + i) * 16;
    union { h8 v8[3]; h2 v2[12]; } W;
    W.v8[0] = *(const h8*)(wrow);
    W.v8[1] = *(const h8*)(wrow + 4);
    W.v8[2] = *(const h8*)(wrow + 8);
    a0 = dot2(lo2(r0a), W.v2[0], a0);  a1 = dot2(hi2(r0a), W.v2[0], a1);
    a0 = dot2(hi2(r0a), W.v2[1], a0);  a1 = dot2(lo2(r0b), W.v2[1], a1);
    a0 = dot2(lo2(r0b), W.v2[2], a0);  a1 = dot2(hi2(r0b), W.v2[2], a1);
    a0 = dot2(lo2(r1a), W.v2[3], a0);  a1 = dot2(hi2(r1a), W.v2[3], a1);
    a0 = dot2(hi2(r1a), W.v2[4], a0);  a1 = dot2(lo2(r1b), W.v2[4], a1);
    a0 = dot2(lo2(r1b), W.v2[5], a0);  a1 = dot2(hi2(r1b), W.v2[5], a1);
    a0 = dot2(lo2(r2a), W.v2[6], a0);  a1 = dot2(hi2(r2a), W.v2[6], a1);
    a0 = dot2(hi2(r2a), W.v2[7], a0);  a1 = dot2(lo2(r2b), W.v2[7], a1);
    a0 = dot2(lo2(r2b), W.v2[8], a0);  a1 = dot2(hi2(r2b), W.v2[8], a1);
  }
  __syncthreads();                      // planes dead; cb overlays them
  float* cb = (float*)smem;             // [288][2]
  if (sub == 1) { cb[r * 2] = a0; cb[r * 2 + 1] = a1; }
  __syncthreads();
  if (sub == 0) {
    size_t idx = ((size_t)(b * C_IN + oc) * HW_) + y * 24 + x0;
    float2 xr = *reinterpret_cast<const float2*>(x + idx);
    const float inv = 1.f / 4096.f;
    float2 v;
    v.x = fmaf(a0 + cb[r * 2],     inv, xr.x);
    v.y = fmaf(a1 + cb[r * 2 + 1], inv, xr.y);
    *reinterpret_cast<float2*>(out + idx) = v;
  }
}

// ---------------- launch ---------------------------------------------------
extern "C" void kernel_launch(void* const* d_in, const int* in_sizes, int n_in,
                              void* d_out, int out_size, void* d_ws, size_t ws_size,
                              hipStream_t stream) {
  const float* x     = (const float*)d_in[0];
  const float* gamma = (const float*)d_in[1];
  const float* beta  = (const float*)d_in[2];
  const float* w_qkv = (const float*)d_in[3];
  const float* w_out = (const float*)d_in[4];
  float* out = (float*)d_out;

  h2* xh   = (h2*)d_ws;
  h2* wqh  = xh + XH_N;
  h2* woh  = wqh + WQH_N;
  h2* outv = woh + WOH_N;

  stats_pack_kernel<<<256, 256, 0, stream>>>(x, gamma, beta, w_qkv, w_out, xh, wqh, woh);
  qkv_attn_kernel<<<256, 576, 0, stream>>>(xh, wqh, outv);
  conv_out_kernel<<<256, 576, 0, stream>>>(outv, woh, x, out);
}

// Round 13
// 26.445 us; speedup vs baseline: 1.2450x; 1.2450x over previous
//
#include <hip/hip_runtime.h>
#include <math.h>

#define B_SZ 4
#define C_IN 64
#define HW_ 576
#define PPLANE 728                    // 26*28 padded plane of h2 (channel pair)
#define XH_N   (B_SZ * 32 * PPLANE)   // 93184

typedef _Float16 h2 __attribute__((ext_vector_type(2)));
typedef _Float16 h8 __attribute__((ext_vector_type(8)));

static __device__ __forceinline__ float dot2(h2 a, h2 b, float c) {
#if __has_builtin(__builtin_amdgcn_fdot2)
  return __builtin_amdgcn_fdot2(a, b, c, false);
#else
  return c + (float)a.x * (float)b.x + (float)a.y * (float)b.y;
#endif
}

static __device__ __forceinline__ float frcp(float d) {
#if __has_builtin(__builtin_amdgcn_rcpf)
  return __builtin_amdgcn_rcpf(d);
#else
  return 1.0f / d;
#endif
}

// ---------------- K1: BN stats (redundant per block) + pack x to f16 -------
// 128 blocks: (b = bid/32, icp = bid%32). Weight packing moved into K2/K3.
__global__ __launch_bounds__(256)
void stats_pack_kernel(const float* __restrict__ x, const float* __restrict__ gamma,
                       const float* __restrict__ beta, h2* __restrict__ xh) {
  const int bid = blockIdx.x, tid = threadIdx.x;
  const int icp = bid & 31, b = bid >> 5;
  __shared__ float rs[4], rss[4], ab[4];
  const int c = icp * 2 + (tid >> 7);
  float s = 0.f, ss = 0.f;
  for (int i = (tid & 127); i < B_SZ * HW_; i += 128) {
    int b2 = i / HW_, px = i - b2 * HW_;
    float v = x[(b2 * C_IN + c) * HW_ + px];
    s += v; ss = fmaf(v, v, ss);
  }
#pragma unroll
  for (int off = 32; off > 0; off >>= 1) {
    s += __shfl_down(s, off); ss += __shfl_down(ss, off);
  }
  if ((tid & 63) == 0) { rs[tid >> 6] = s; rss[tid >> 6] = ss; }
  __syncthreads();
  if (tid < 2) {
    float S = rs[tid * 2] + rs[tid * 2 + 1], SS = rss[tid * 2] + rss[tid * 2 + 1];
    const float inv_n = 1.f / (B_SZ * HW_);
    float mean = S * inv_n;
    float var  = SS * inv_n - mean * mean;
    float a = rsqrtf(var + 1e-5f) * gamma[icp * 2 + tid];
    ab[tid * 2] = a;
    ab[tid * 2 + 1] = fmaf(-mean, a, beta[icp * 2 + tid]);
  }
  __syncthreads();
  const float a0 = ab[0], b0 = ab[1], a1 = ab[2], b1 = ab[3];
  h2* plane = xh + (size_t)(b * 32 + icp) * PPLANE;
  const float* src0 = x + (size_t)(b * C_IN + icp * 2) * HW_;
  for (int e = tid; e < PPLANE; e += 256) {
    int rrow = e / 28, ecol = e - rrow * 28;
    int yy = rrow - 1, xx = ecol - 1;
    float f0 = 0.f, f1 = 0.f;
    if ((unsigned)yy < 24u && (unsigned)xx < 24u) {
      f0 = fmaf(src0[yy * 24 + xx],       a0, b0);
      f1 = fmaf(src0[HW_ + yy * 24 + xx], a1, b1);
    }
    h2 v; v.x = (_Float16)f0; v.y = (_Float16)f1;
    plane[e] = v;
  }
}

// ---------------- K2: fused qkv conv + barycentric rank-1 attention --------
// 576 thr = 4 K-quarters x 144 pixel-quads. Thread (sub, r): y=r/6,
// x0=4*(r%6). Row window = entries x0..x0+7 (pixels x0-1..x0+6), 16B-aligned
// -> 2 h8 loads/row, 6 VMEM/icp, 8 icp/thread. Weights packed f32->LDS here.
__global__ __launch_bounds__(576)
void qkv_attn_kernel(const h2* __restrict__ xh, const float* __restrict__ wq,
                     h2* __restrict__ outv) {
  const int bid = blockIdx.x, tid = threadIdx.x;
  const int b = bid >> 6, c = bid & 63;
  const int sub = tid / 144;
  const int r = tid - sub * 144;
  const int y = r / 6, x0 = (r % 6) * 4;

  __shared__ __align__(16) char smem[43424];
  h2*    Wl  = (h2*)smem;                 // [32 icp][32 h2] (27 used) 4096B
  float* cb  = (float*)(smem + 4096);     // [9][144][4] f32, 20736B
  float2* kvs = (float2*)(smem + 24832);  // 576 float2
  float* qs  = (float*)(smem + 29440);    // 576 f32
  float* red = (float*)(smem + 31744);    // 20
  float* FGf = (float*)(smem + 31824);    // 18
  float* red2 = (float*)(smem + 31904);   // [144][20] 11520B

  // pack this block's weights f32 -> f16 LDS (oc = {c, 64+c, 128+c})
  for (int j = tid; j < 864; j += 576) {
    int icp = j / 27, rem = j - icp * 27;
    int o = rem / 9, t = rem - o * 9;
    int oc = c + 64 * o;
    h2 v;
    v.x = (_Float16)wq[(oc * C_IN + 2 * icp) * 9 + t];
    v.y = (_Float16)wq[(oc * C_IN + 2 * icp + 1) * 9 + t];
    Wl[icp * 32 + rem] = v;
  }
  __syncthreads();

  float acc[3][4] = {{0.f,0.f,0.f,0.f},{0.f,0.f,0.f,0.f},{0.f,0.f,0.f,0.f}};
  const int icp0 = sub * 8;
  const h2* dbase = xh + ((size_t)(b * 32 + icp0) * PPLANE + y * 28 + x0);
#pragma unroll
  for (int i = 0; i < 8; ++i) {
    const h2* dp = dbase + i * PPLANE;
    // one h8 = 4 h2 entries (16B). Two per row cover entries x0..x0+7.
    union { h8 v8[2]; h2 v2[8]; } R0, R1, R2;
    R0.v8[0] = *(const h8*)(dp);      R0.v8[1] = *(const h8*)(dp + 4);
    R1.v8[0] = *(const h8*)(dp + 28); R1.v8[1] = *(const h8*)(dp + 32);
    R2.v8[0] = *(const h8*)(dp + 56); R2.v8[1] = *(const h8*)(dp + 60);
    const h2* wrow = Wl + (icp0 + i) * 32;
    union { h8 v8[7]; h2 v2[28]; } W;      // 56 halves both ways
#pragma unroll
    for (int j8 = 0; j8 < 7; ++j8) W.v8[j8] = *(const h8*)(wrow + j8 * 4);
#pragma unroll
    for (int o = 0; o < 3; ++o) {
#pragma unroll
      for (int p = 0; p < 4; ++p) {
        float a = acc[o][p];
        a = dot2(R0.v2[p + 0], W.v2[o * 9 + 0], a);
        a = dot2(R0.v2[p + 1], W.v2[o * 9 + 1], a);
        a = dot2(R0.v2[p + 2], W.v2[o * 9 + 2], a);
        a = dot2(R1.v2[p + 0], W.v2[o * 9 + 3], a);
        a = dot2(R1.v2[p + 1], W.v2[o * 9 + 4], a);
        a = dot2(R1.v2[p + 2], W.v2[o * 9 + 5], a);
        a = dot2(R2.v2[p + 0], W.v2[o * 9 + 6], a);
        a = dot2(R2.v2[p + 1], W.v2[o * 9 + 7], a);
        a = dot2(R2.v2[p + 2], W.v2[o * 9 + 8], a);
        acc[o][p] = a;
      }
    }
  }
  __syncthreads();
  if (sub != 0) {
    const int base = (sub - 1) * 3 * 576;
#pragma unroll
    for (int o = 0; o < 3; ++o)
#pragma unroll
      for (int p = 0; p < 4; ++p)
        cb[base + o * 576 + r * 4 + p] = acc[o][p];
  }
  __syncthreads();
  const float scale_l2e = 0.125f * 1.44269504088896341f;  // 1/sqrt(64)*log2(e)
  if (sub == 0) {
#pragma unroll
    for (int p = 0; p < 4; ++p) {
      float qv = acc[0][p] + cb[0 * 576 + r * 4 + p]
               + cb[3 * 576 + r * 4 + p] + cb[6 * 576 + r * 4 + p];
      float kv = acc[1][p] + cb[1 * 576 + r * 4 + p]
               + cb[4 * 576 + r * 4 + p] + cb[7 * 576 + r * 4 + p];
      float vv = acc[2][p] + cb[2 * 576 + r * 4 + p]
               + cb[5 * 576 + r * 4 + p] + cb[8 * 576 + r * 4 + p];
      qs[4 * r + p] = qv * scale_l2e;        // pixel = 4r + p
      kvs[4 * r + p] = make_float2(kv, vv);
    }
  }
  __syncthreads();

  // ---- barycentric rank-1 attention (thread tid = pixel tid) ----
  const float s = qs[tid];
  float smax = s, smin = s;
#pragma unroll
  for (int off = 32; off > 0; off >>= 1) {
    smax = fmaxf(smax, __shfl_down(smax, off));
    smin = fminf(smin, __shfl_down(smin, off));
  }
  const int wid = tid >> 6;
  if ((tid & 63) == 0) { red[wid] = smax; red[10 + wid] = smin; }
  __syncthreads();
  smax = red[0]; smin = red[10];
#pragma unroll
  for (int w = 1; w < 9; ++w) {
    smax = fmaxf(smax, red[w]); smin = fminf(smin, red[10 + w]);
  }
  const float cc = 0.5f * (smax + smin);
  const float rr = fmaxf(0.5f * (smax - smin), 1e-6f);
  const float COS[9] = { 0.98480775f,  0.86602540f,  0.64278761f,  0.34202014f, 0.f,
                        -0.34202014f, -0.64278761f, -0.86602540f, -0.98480775f };
  const float WJ[9]  = { 0.17364818f, -0.5f,  0.76604444f, -0.93969262f, 1.f,
                        -0.93969262f, 0.76604444f, -0.5f, 0.17364818f };
  float xj[9];
#pragma unroll
  for (int j = 0; j < 9; ++j) xj[j] = fmaf(rr, COS[j], cc);

  const float kk = kvs[tid].x, vv = kvs[tid].y;
  float fj[9], gj[9];
#pragma unroll
  for (int j = 0; j < 9; ++j) {
    float E = __builtin_amdgcn_exp2f(xj[j] * kk);
    gj[j] = E; fj[j] = E * vv;
  }
#pragma unroll
  for (int j = 0; j < 9; ++j) {
    fj[j] += __shfl_xor(fj[j], 1); gj[j] += __shfl_xor(gj[j], 1);
    fj[j] += __shfl_xor(fj[j], 2); gj[j] += __shfl_xor(gj[j], 2);
  }
  if ((tid & 3) == 0) {
    const int row = tid >> 2;       // 0..143
#pragma unroll
    for (int j = 0; j < 9; ++j) {
      red2[row * 20 + j] = fj[j];
      red2[row * 20 + 9 + j] = gj[j];
    }
  }
  __syncthreads();
  if (tid < 144) {
    const int j = tid >> 3, chunk = tid & 7;   // j in 0..17
    float sum = 0.f;
#pragma unroll
    for (int i = 0; i < 18; ++i) sum += red2[(chunk + 8 * i) * 20 + j];
    sum += __shfl_xor(sum, 1);
    sum += __shfl_xor(sum, 2);
    sum += __shfl_xor(sum, 4);
    if (chunk == 0) FGf[j] = sum;
  }
  __syncthreads();

  float num = 0.f, den = 0.f;
#pragma unroll
  for (int j = 0; j < 9; ++j) {
    float d = s - xj[j];
    d = copysignf(fmaxf(fabsf(d), 1e-7f), d);
    float mu = WJ[j] * frcp(d);
    num = fmaf(mu, FGf[j], num);
    den = fmaf(mu, FGf[9 + j], den);
  }
  float outval = num / den;

  const int icp = c >> 1, hc = c & 1;
  _Float16* plane = reinterpret_cast<_Float16*>(outv + ((size_t)(b * 32) + icp) * PPLANE);
  const int yy = tid / 24, xx = tid - yy * 24;
  plane[((yy + 1) * 28 + (xx + 1)) * 2 + hc] = (_Float16)outval;
  if (tid < 100) {  // zero halo (cols 26,27 never used by dot2s)
    int rrow, e;
    if (tid < 26)      { rrow = 0;            e = tid; }
    else if (tid < 52) { rrow = 25;           e = tid - 26; }
    else if (tid < 76) { rrow = tid - 52 + 1; e = 0; }
    else               { rrow = tid - 76 + 1; e = 25; }
    plane[(rrow * 28 + e) * 2 + hc] = (_Float16)0.f;
  }
}

// ---------------- K3: out conv (OCG=1) + residual + final store ------------
__global__ __launch_bounds__(576)
void conv_out_kernel(const h2* __restrict__ outv, const float* __restrict__ wo,
                     const float* __restrict__ x, float* __restrict__ out) {
  const int bid = blockIdx.x, tid = threadIdx.x;
  const int b = bid >> 6, oc = bid & 63;
  const int sub = tid / 144;
  const int r = tid - sub * 144;
  const int y = r / 6, x0 = (r % 6) * 4;

  __shared__ __align__(16) char smem[8960];
  h2*    Wl = (h2*)smem;               // [32 icp][16 h2] (9 used) 2048B
  float* cb = (float*)(smem + 2048);   // [3][144][4] f32, 6912B

  for (int j = tid; j < 288; j += 576) {
    int icp = j / 9, t = j - icp * 9;
    h2 v;  // scale 4096: dodge f16 subnormals (w_out ~ 7e-5)
    v.x = (_Float16)(wo[(oc * C_IN + 2 * icp) * 9 + t] * 4096.f);
    v.y = (_Float16)(wo[(oc * C_IN + 2 * icp + 1) * 9 + t] * 4096.f);
    Wl[icp * 16 + t] = v;
  }
  __syncthreads();

  float acc[4] = {0.f, 0.f, 0.f, 0.f};
  const int icp0 = sub * 8;
  const h2* dbase = outv + ((size_t)(b * 32 + icp0) * PPLANE + y * 28 + x0);
#pragma unroll
  for (int i = 0; i < 8; ++i) {
    const h2* dp = dbase + i * PPLANE;
    union { h8 v8[2]; h2 v2[8]; } R0, R1, R2;
    R0.v8[0] = *(const h8*)(dp);      R0.v8[1] = *(const h8*)(dp + 4);
    R1.v8[0] = *(const h8*)(dp + 28); R1.v8[1] = *(const h8*)(dp + 32);
    R2.v8[0] = *(const h8*)(dp + 56); R2.v8[1] = *(const h8*)(dp + 60);
    const h2* wrow = Wl + (icp0 + i) * 16;
    union { h8 v8[3]; h2 v2[12]; } W;    // 24 halves both ways
    W.v8[0] = *(const h8*)(wrow);
    W.v8[1] = *(const h8*)(wrow + 4);
    W.v8[2] = *(const h8*)(wrow + 8);
#pragma unroll
    for (int p = 0; p < 4; ++p) {
      float a = acc[p];
      a = dot2(R0.v2[p + 0], W.v2[0], a);
      a = dot2(R0.v2[p + 1], W.v2[1], a);
      a = dot2(R0.v2[p + 2], W.v2[2], a);
      a = dot2(R1.v2[p + 0], W.v2[3], a);
      a = dot2(R1.v2[p + 1], W.v2[4], a);
      a = dot2(R1.v2[p + 2], W.v2[5], a);
      a = dot2(R2.v2[p + 0], W.v2[6], a);
      a = dot2(R2.v2[p + 1], W.v2[7], a);
      a = dot2(R2.v2[p + 2], W.v2[8], a);
      acc[p] = a;
    }
  }
  __syncthreads();
  if (sub != 0) {
    const int base = ((sub - 1) * 144 + r) * 4;
#pragma unroll
    for (int p = 0; p < 4; ++p) cb[base + p] = acc[p];
  }
  __syncthreads();
  if (sub == 0) {
    size_t idx = ((size_t)(b * C_IN + oc) * HW_) + 4 * r;
    float4 xr = *reinterpret_cast<const float4*>(x + idx);
    const float inv = 1.f / 4096.f;
    float4 v;
    v.x = fmaf(acc[0] + cb[(0 * 144 + r) * 4 + 0] + cb[(1 * 144 + r) * 4 + 0] + cb[(2 * 144 + r) * 4 + 0], inv, xr.x);
    v.y = fmaf(acc[1] + cb[(0 * 144 + r) * 4 + 1] + cb[(1 * 144 + r) * 4 + 1] + cb[(2 * 144 + r) * 4 + 1], inv, xr.y);
    v.z = fmaf(acc[2] + cb[(0 * 144 + r) * 4 + 2] + cb[(1 * 144 + r) * 4 + 2] + cb[(2 * 144 + r) * 4 + 2], inv, xr.z);
    v.w = fmaf(acc[3] + cb[(0 * 144 + r) * 4 + 3] + cb[(1 * 144 + r) * 4 + 3] + cb[(2 * 144 + r) * 4 + 3], inv, xr.w);
    *reinterpret_cast<float4*>(out + idx) = v;
  }
}

// ---------------- launch ---------------------------------------------------
extern "C" void kernel_launch(void* const* d_in, const int* in_sizes, int n_in,
                              void* d_out, int out_size, void* d_ws, size_t ws_size,
                              hipStream_t stream) {
  const float* x     = (const float*)d_in[0];
  const float* gamma = (const float*)d_in[1];
  const float* beta  = (const float*)d_in[2];
  const float* w_qkv = (const float*)d_in[3];
  const float* w_out = (const float*)d_in[4];
  float* out = (float*)d_out;

  h2* xh   = (h2*)d_ws;
  h2* outv = xh + XH_N;

  stats_pack_kernel<<<128, 256, 0, stream>>>(x, gamma, beta, xh);
  qkv_attn_kernel<<<256, 576, 0, stream>>>(xh, w_qkv, outv);
  conv_out_kernel<<<256, 576, 0, stream>>>(outv, w_out, x, out);
}